// Round 8
// baseline (297.256 us; speedup 1.0000x reference)
//
#include <hip/hip_runtime.h>
#include <math.h>
#include <stdint.h>

#define NCLS   80
#define NPTS   8400
#define KEEP   100
#define PRETOPK 5000
#define NB     8
#define THRBITS 0x3C23D70Au   // bits of 0.01f (scores are positive floats -> int-ordered)

#define TBS    512            // block size
#define NREG   17             // ceil(8400/512)
#define CAPF   512            // candidate cap
#define NEEDF  192u           // selection target
#define MTX    256            // suppression-matrix size

#define NREGT  16             // ceil(8000/512)
#define CAPT   512

__device__ __forceinline__ float sigmoidf_(float x) { return 1.0f / (1.0f + expf(-x)); }

__device__ __forceinline__ uint32_t score_key(int n, int b, int c,
        const float* cls0, const float* obj0, const float* cls1, const float* obj1,
        const float* cls2, const float* obj2) {
    const float *clsP, *objP; int base, HW;
    if (n < 6400)      { clsP = cls0; objP = obj0; base = n;        HW = 6400; }
    else if (n < 8000) { clsP = cls1; objP = obj1; base = n - 6400; HW = 1600; }
    else               { clsP = cls2; objP = obj2; base = n - 8000; HW = 400;  }
    float cv = clsP[((size_t)b * NCLS + c) * HW + base];
    float ov = objP[(size_t)b * HW + base];
    return __float_as_uint(sigmoidf_(cv) * sigmoidf_(ov));
}

__device__ __forceinline__ float4 decode_one(int n, int b,
        const float* bb0, const float* bb1, const float* bb2) {
    const float* bb; int base, HW, x, y; float s;
    if (n < 6400)      { bb = bb0; base = n;        HW = 6400; s = 8.f;  y = base / 80; x = base - y * 80; }
    else if (n < 8000) { bb = bb1; base = n - 6400; HW = 1600; s = 16.f; y = base / 40; x = base - y * 40; }
    else               { bb = bb2; base = n - 8000; HW = 400;  s = 32.f; y = base / 20; x = base - y * 20; }
    const float* p = bb + (size_t)b * 4 * HW + base;
    float v0 = p[0], v1 = p[HW], v2 = p[2 * HW], v3 = p[3 * HW];
    float cx = v0 * s + x * s, cy = v1 * s + y * s;
    float w = expf(v2) * s, h = expf(v3) * s;
    return make_float4(cx - 0.5f * w, cy - 0.5f * h, cx + 0.5f * w, cy + 0.5f * h);
}

__device__ __forceinline__ bool iou_gt(float4 a, float4 c) {
    float tlx = fmaxf(a.x, c.x), tly = fmaxf(a.y, c.y);
    float brx = fminf(a.z, c.z), bry = fminf(a.w, c.w);
    float w = fmaxf(brx - tlx, 0.f), h = fmaxf(bry - tly, 0.f);
    float inter = w * h;
    float a1 = (a.z - a.x) * (a.w - a.y);
    float a2 = (c.z - c.x) * (c.w - c.y);
    return inter / (a1 + a2 - inter + 1e-6f) > 0.65f;
}

// parallel crossing scan (wave 0 only). shr[1]=1 -> refine; else shr[0]=Tsel.
__device__ void scan_cross_fast(const uint32_t* hist, int nb, uint32_t need, uint32_t cap,
                                uint32_t carry, uint32_t prefix, int shift, int level,
                                uint32_t* shr, int lane) {
    uint32_t csum;
    if (nb == 4096) {
        uint32_t s = 0;
        int cb = lane << 6;
        #pragma unroll 8
        for (int i = 0; i < 64; ++i) s += hist[cb + i];
        csum = s;
    } else {
        csum = hist[lane];
    }
    uint32_t suf = csum;
    #pragma unroll
    for (int d = 1; d < 64; d <<= 1) {
        uint32_t t = (uint32_t)__shfl_down((int)suf, d);
        if (lane + d < 64) suf += t;
    }
    unsigned long long m = __ballot(carry + suf >= need);
    if (!m) { if (lane == 0) { shr[1] = 0u; shr[0] = 0u; } return; }
    int l1 = 63 - __clzll(m);
    uint32_t sufL1 = (uint32_t)__shfl((int)suf, l1);
    uint32_t csumL1 = (uint32_t)__shfl((int)csum, l1);
    uint32_t carry2 = carry + sufL1 - csumL1;
    int foundBin; uint32_t cAbove, bCnt;
    if (nb == 4096) {
        int cb = l1 << 6;
        uint32_t c2 = hist[cb + lane];
        uint32_t suf2 = c2;
        #pragma unroll
        for (int d = 1; d < 64; d <<= 1) {
            uint32_t t = (uint32_t)__shfl_down((int)suf2, d);
            if (lane + d < 64) suf2 += t;
        }
        unsigned long long m2 = __ballot(carry2 + suf2 >= need);
        int l2 = 63 - __clzll(m2);
        foundBin = cb + l2;
        uint32_t suf2L = (uint32_t)__shfl((int)suf2, l2);
        uint32_t c2L = (uint32_t)__shfl((int)c2, l2);
        cAbove = carry2 + suf2L - c2L;
        bCnt = c2L;
    } else {
        foundBin = l1; cAbove = carry2; bCnt = csumL1;
    }
    if (lane == 0) {
        uint32_t cntIncl = cAbove + bCnt;
        if (cntIncl <= cap) { shr[1] = 0u; shr[0] = prefix | ((uint32_t)foundBin << shift); }
        else if (level == 2) { shr[1] = 0u; shr[0] = (prefix | (uint32_t)foundBin) + 1u; }
        else { shr[1] = 1u; shr[2] = prefix | ((uint32_t)foundBin << shift); shr[3] = cAbove; }
    }
}

// ================================================================ fused kernel
__global__ __launch_bounds__(TBS)
void yolox_all(const float* __restrict__ cls0, const float* __restrict__ bb0, const float* __restrict__ obj0,
               const float* __restrict__ cls1, const float* __restrict__ bb1, const float* __restrict__ obj1,
               const float* __restrict__ cls2, const float* __restrict__ bb2, const float* __restrict__ obj2,
               float* __restrict__ keptScore, float4* __restrict__ keptBox,
               uint32_t* __restrict__ imgCnt, float* __restrict__ out) {
    __shared__ uint32_t sHist[4096];                          // 16 KB
    __shared__ __align__(16) unsigned long long cPack[CAPF + 2]; // 4.1 KB
    __shared__ uint32_t sKeyS[CAPF];                          // 2 KB
    __shared__ uint16_t sIdxS[CAPF];                          // 1 KB
    __shared__ float4   bBoxS[CAPF];                          // 8 KB
    __shared__ unsigned long long colM[MTX][4];               // 8 KB
    __shared__ uint32_t shr[4];
    __shared__ unsigned long long sh64;
    __shared__ int isLastSh;

    int bc = blockIdx.x;
    int b = bc / NCLS, c = bc - b * NCLS;
    int tid = threadIdx.x, lane = tid & 63;

    // ---- phase 1: keygen into registers
    uint32_t rKey[NREG];
    #pragma unroll
    for (int i = 0; i < NREG; ++i) {
        int n = tid + i * TBS;
        rKey[i] = (n < NPTS) ? score_key(n, b, c, cls0, obj0, cls1, obj1, cls2, obj2) : 0u;
    }

    // ---- phase 2: exact radix threshold selection
    uint32_t prefix = 0, carry = 0, Tsel = 0;
    for (int level = 0;; ++level) {
        int shift = (level == 0) ? 18 : (level == 1 ? 6 : 0);
        int nb = (level == 2) ? 64 : 4096;
        __syncthreads();
        for (int i = tid; i < nb; i += TBS) sHist[i] = 0;
        __syncthreads();
        #pragma unroll
        for (int i = 0; i < NREG; ++i) {
            uint32_t k = rKey[i];
            if (k > THRBITS) {
                if (level == 0) atomicAdd(&sHist[k >> 18], 1u);
                else if (level == 1) { if ((k >> 18) == (prefix >> 18)) atomicAdd(&sHist[(k >> 6) & 0xFFFu], 1u); }
                else { if ((k >> 6) == (prefix >> 6)) atomicAdd(&sHist[k & 0x3Fu], 1u); }
            }
        }
        __syncthreads();
        if (tid < 64) scan_cross_fast(sHist, nb, NEEDF, CAPF, carry, prefix, shift, level, shr, lane);
        __syncthreads();
        if (shr[1] == 0u) { Tsel = shr[0]; break; }
        prefix = shr[2]; carry = shr[3];
    }
    __syncthreads();
    if (tid == 0) shr[3] = 0u;
    __syncthreads();

    // ---- phase 3: compact (packed u64: key<<32 | (0xFFFF-idx); order = pack desc)
    #pragma unroll
    for (int i = 0; i < NREG; ++i) {
        uint32_t k = rKey[i];
        if (k > THRBITS && k >= Tsel) {
            uint32_t s = atomicAdd(&shr[3], 1u);
            if (s < CAPF) cPack[s] = ((unsigned long long)k << 32) | (uint32_t)(0xFFFFu - (tid + i * TBS));
        }
    }
    __syncthreads();
    int cnt = (int)shr[3]; if (cnt > CAPF) cnt = CAPF;
    if (tid == 0) { cPack[cnt] = 0ull; cPack[cnt + 1] = 0ull; }
    __syncthreads();

    // ---- phase 4: rank-sort (participating waves only)
    {
        bool h0 = tid < cnt;
        if (tid < ((cnt + 63) & ~63)) {
            unsigned long long my = h0 ? cPack[tid] : 0ull;
            int r0 = 0;
            const ulonglong2* cp2 = (const ulonglong2*)cPack;
            int n2 = (cnt + 1) >> 1;
            for (int j2 = 0; j2 < n2; ++j2) {
                ulonglong2 pp = cp2[j2];
                r0 += (pp.x > my) + (pp.y > my);
            }
            if (h0) {
                sKeyS[r0] = (uint32_t)(my >> 32);
                sIdxS[r0] = (uint16_t)(0xFFFFu - (uint32_t)(my & 0xFFFFu));
            }
        }
        __syncthreads();
    }

    // ---- phase 5: gather + inline-decode candidate boxes
    for (int s = tid; s < cnt; s += TBS) bBoxS[s] = decode_one(sIdxS[s], b, bb0, bb1, bb2);
    __syncthreads();

    // ---- phase 6: column suppression bitmatrix, tiled over all 8 waves
    int lim = (cnt < MTX) ? cnt : MTX;
    {
        int w = tid >> 6, l = lane;
        const int fullCg[6] = {1, 2, 2, 3, 3, 3};
        const int fullRb[6] = {0, 0, 1, 0, 1, 2};
        if (w < 6) {
            int cg = fullCg[w], rb = fullRb[w];
            int cand = (cg << 6) + l;
            unsigned long long m = 0ull;
            if (cand < lim) {
                float4 bcx = bBoxS[cand];
                int j0 = rb << 6;
                for (int jj = 0; jj < 64; ++jj)
                    if (iou_gt(bBoxS[j0 + jj], bcx)) m |= 1ull << jj;
            }
            colM[(cg << 6) + l][rb] = m;
        } else {
            int d0 = (w == 6) ? 0 : 1;
            #pragma unroll
            for (int t = 0; t < 2; ++t) {
                int cg = d0 + 2 * t;
                int cand = (cg << 6) + l;
                unsigned long long m = 0ull;
                if (cand < lim) {
                    float4 bcx = bBoxS[cand];
                    int j0 = cg << 6;
                    for (int jj = 0; jj < l; ++jj)
                        if (iou_gt(bBoxS[j0 + jj], bcx)) m |= 1ull << jj;
                }
                colM[(cg << 6) + l][cg] = m;
            }
        }
    }
    __syncthreads();

    // ---- phase 7: serial walk on wave 0 — ballot + register bit ops only
    float4 kb0 = make_float4(0.f, 0.f, 0.f, 0.f), kb1 = kb0;
    float ks0 = -1.0f, ks1 = -1.0f;
    int K = 0;
    if (tid < 64) {
        unsigned long long cA[4], cB[4], cC[4], cD[4];
        #pragma unroll
        for (int rb = 0; rb < 4; ++rb) {
            cA[rb] = colM[lane][rb];
            cB[rb] = colM[64 + lane][rb];
            cC[rb] = colM[128 + lane][rb];
            cD[rb] = colM[192 + lane][rb];
        }
        bool a0 = lane < lim, a1 = 64 + lane < lim, a2 = 128 + lane < lim, a3 = 192 + lane < lim;
        int kIA = -1, kIB = -1;
        while (K < KEEP) {
            unsigned long long m0 = __ballot(a0);
            unsigned long long m1 = __ballot(a1);
            unsigned long long m2 = __ballot(a2);
            unsigned long long m3 = __ballot(a3);
            int i;
            if (m0)      i = (int)__ffsll(m0) - 1;
            else if (m1) i = 64 + (int)__ffsll(m1) - 1;
            else if (m2) i = 128 + (int)__ffsll(m2) - 1;
            else if (m3) i = 192 + (int)__ffsll(m3) - 1;
            else break;
            int rb = i >> 6, il = i & 63;
            unsigned long long w0, w1, w2, w3;
            if (rb == 0)      { w0 = cA[0]; w1 = cB[0]; w2 = cC[0]; w3 = cD[0]; }
            else if (rb == 1) { w0 = cA[1]; w1 = cB[1]; w2 = cC[1]; w3 = cD[1]; }
            else if (rb == 2) { w0 = cA[2]; w1 = cB[2]; w2 = cC[2]; w3 = cD[2]; }
            else              { w0 = cA[3]; w1 = cB[3]; w2 = cC[3]; w3 = cD[3]; }
            if (rb == 0      && lane == il) a0 = false;
            else if (rb == 1 && lane == il) a1 = false;
            else if (rb == 2 && lane == il) a2 = false;
            else if (rb == 3 && lane == il) a3 = false;
            a0 = a0 && !((w0 >> il) & 1ull);
            a1 = a1 && !((w1 >> il) & 1ull);
            a2 = a2 && !((w2 >> il) & 1ull);
            a3 = a3 && !((w3 >> il) & 1ull);
            if (K < 64) { if (lane == K) kIA = i; }
            else        { if (lane == K - 64) kIB = i; }
            K++;
        }
        if (kIA >= 0) { kb0 = bBoxS[kIA]; ks0 = __uint_as_float(sKeyS[kIA]); }
        if (kIB >= 0) { kb1 = bBoxS[kIB]; ks1 = __uint_as_float(sKeyS[kIB]); }
        // mid-walk beyond matrix (cnt > MTX; rare)
        for (int i = lim; i < cnt && K < KEEP; ++i) {
            float4 bx = bBoxS[i];
            bool sup = false;
            if (lane < K)      sup = iou_gt(bx, kb0);
            if (64 + lane < K) sup = sup || iou_gt(bx, kb1);
            if (!__any(sup ? 1 : 0)) {
                float sc = __uint_as_float(sKeyS[i]);
                if (K < 64) { if (lane == K)      { kb0 = bx; ks0 = sc; } }
                else        { if (lane == K - 64) { kb1 = bx; ks1 = sc; } }
                K++;
            }
        }
        if (lane == 0) {
            shr[0] = (uint32_t)K;
            shr[1] = (uint32_t)cnt;
            shr[2] = (cnt > 0) ? sKeyS[cnt - 1] : 0xFFFFFFFFu;
            shr[3] = (cnt > 0) ? (uint32_t)sIdxS[cnt - 1] : 0xFFFFFFFFu;
        }
    }
    __syncthreads();
    int Kall = (int)shr[0]; int e = (int)shr[1];
    uint32_t cK = shr[2], cI = shr[3];

    // ---- phase 8: exact continuation via block argmax (rare)
    if (Kall < KEEP && e < PRETOPK) {
        for (;;) {
            if (tid == 0) sh64 = 0ull;
            __syncthreads();
            unsigned long long best = 0ull;
            #pragma unroll
            for (int i = 0; i < NREG; ++i) {
                uint32_t k = rKey[i]; int n = tid + i * TBS;
                if (k > THRBITS && (k < cK || (k == cK && (uint32_t)n > cI))) {
                    unsigned long long v = ((unsigned long long)k << 32) | (unsigned long long)(NPTS - 1 - n);
                    if (v > best) best = v;
                }
            }
            if (best) atomicMax(&sh64, best);
            __syncthreads();
            unsigned long long bv = sh64;
            if (bv == 0ull) break;
            uint32_t k = (uint32_t)(bv >> 32);
            int n = NPTS - 1 - (int)(bv & 0xFFFFFFFFull);
            if (tid < 64) {
                float4 bx = decode_one(n, b, bb0, bb1, bb2);
                bool sup = false;
                if (lane < K)      sup = iou_gt(bx, kb0);
                if (64 + lane < K) sup = sup || iou_gt(bx, kb1);
                if (!__any(sup ? 1 : 0)) {
                    float sc = __uint_as_float(k);
                    if (K < 64) { if (lane == K)      { kb0 = bx; ks0 = sc; } }
                    else        { if (lane == K - 64) { kb1 = bx; ks1 = sc; } }
                    K++;
                }
                if (lane == 0) shr[0] = (uint32_t)K;
            }
            __syncthreads();
            Kall = (int)shr[0];
            e++; cK = k; cI = (uint32_t)n;
            if (Kall >= KEEP || e >= PRETOPK) break;
        }
    }

    // ---- write per-class results
    if (tid < 64) {
        int off = (b * NCLS + c) * KEEP;
        float4 z = make_float4(0.f, 0.f, 0.f, 0.f);
        keptScore[off + lane] = (lane < K) ? ks0 : -1.0f;
        keptBox[off + lane]   = (lane < K) ? kb0 : z;
        if (64 + lane < KEEP) {
            keptScore[off + 64 + lane] = (64 + lane < K) ? ks1 : -1.0f;
            keptBox[off + 64 + lane]   = (64 + lane < K) ? kb1 : z;
        }
    }
    __syncthreads();

    // ---- last finisher of this image runs the per-image top-100
    __threadfence();
    if (tid == 0) isLastSh = (atomicAdd(&imgCnt[b], 1u) == NCLS - 1);
    __syncthreads();
    if (!isLastSh) return;
    __threadfence();

    const int TOT = NCLS * KEEP;     // 8000
    uint32_t tK[NREGT];
    #pragma unroll
    for (int i = 0; i < NREGT; ++i) {
        int n = tid + i * TBS;
        uint32_t key = 0u;
        if (n < TOT) {                               // <-- restored bounds guard (R7 bug)
            float s = keptScore[b * TOT + n];
            key = (s > 0.f) ? __float_as_uint(s) : 0u;
        }
        tK[i] = key;
    }

    prefix = 0; carry = 0; Tsel = 0;
    for (int level = 0;; ++level) {
        int shift = (level == 0) ? 18 : (level == 1 ? 6 : 0);
        int nb = (level == 2) ? 64 : 4096;
        __syncthreads();
        for (int i = tid; i < nb; i += TBS) sHist[i] = 0;
        __syncthreads();
        #pragma unroll
        for (int i = 0; i < NREGT; ++i) {
            uint32_t k = tK[i];
            if (k > 0u) {
                if (level == 0) atomicAdd(&sHist[k >> 18], 1u);
                else if (level == 1) { if ((k >> 18) == (prefix >> 18)) atomicAdd(&sHist[(k >> 6) & 0xFFFu], 1u); }
                else { if ((k >> 6) == (prefix >> 6)) atomicAdd(&sHist[k & 0x3Fu], 1u); }
            }
        }
        __syncthreads();
        if (tid < 64) scan_cross_fast(sHist, nb, (uint32_t)KEEP, CAPT, carry, prefix, shift, level, shr, lane);
        __syncthreads();
        if (shr[1] == 0u) { Tsel = shr[0]; break; }
        prefix = shr[2]; carry = shr[3];
    }
    __syncthreads();
    if (tid == 0) shr[3] = 0u;
    __syncthreads();
    #pragma unroll
    for (int i = 0; i < NREGT; ++i) {
        uint32_t k = tK[i];
        if (k > 0u && k >= Tsel) {
            uint32_t s = atomicAdd(&shr[3], 1u);
            if (s < CAPT) cPack[s] = ((unsigned long long)k << 32) | (uint32_t)(0xFFFFu - (tid + i * TBS));
        }
    }
    __syncthreads();
    int tcnt = (int)shr[3]; if (tcnt > CAPT) tcnt = CAPT;
    if (tid == 0) { cPack[tcnt] = 0ull; cPack[tcnt + 1] = 0ull; }
    __syncthreads();
    {
        bool h0 = tid < tcnt;
        if (tid < ((tcnt + 63) & ~63)) {
            unsigned long long my = h0 ? cPack[tid] : 0ull;
            int r0 = 0;
            const ulonglong2* cp2 = (const ulonglong2*)cPack;
            int n2 = (tcnt + 1) >> 1;
            for (int j2 = 0; j2 < n2; ++j2) {
                ulonglong2 pp = cp2[j2];
                r0 += (pp.x > my) + (pp.y > my);
            }
            if (h0) {
                sKeyS[r0] = (uint32_t)(my >> 32);
                sIdxS[r0] = (uint16_t)(0xFFFFu - (uint32_t)(my & 0xFFFFu));
            }
        }
        __syncthreads();
    }
    if (tid < KEEP) {
        bool valid = tid < tcnt;
        int fi = valid ? (int)sIdxS[tid] : 0;
        float sc = valid ? __uint_as_float(sKeyS[tid]) : 0.f;
        float4 bx = valid ? keptBox[b * TOT + fi] : make_float4(0.f, 0.f, 0.f, 0.f);
        float cls = valid ? (float)(fi / KEEP) : -1.0f;
        float* boxOut = out + NB + (b * KEEP + tid) * 4;
        boxOut[0] = bx.x; boxOut[1] = bx.y; boxOut[2] = bx.z; boxOut[3] = bx.w;
        out[NB + NB * KEEP * 4 + b * KEEP + tid] = sc;
        out[NB + NB * KEEP * 4 + NB * KEEP + b * KEEP + tid] = cls;
    }
    if (tid == 0) out[b] = (float)((tcnt < KEEP) ? tcnt : KEEP);
}

// ---------------------------------------------------------------- launch
extern "C" void kernel_launch(void* const* d_in, const int* in_sizes, int n_in,
                              void* d_out, int out_size, void* d_ws, size_t ws_size,
                              hipStream_t stream) {
    const float* cls0 = (const float*)d_in[0];
    const float* bb0  = (const float*)d_in[1];
    const float* obj0 = (const float*)d_in[2];
    const float* cls1 = (const float*)d_in[3];
    const float* bb1  = (const float*)d_in[4];
    const float* obj1 = (const float*)d_in[5];
    const float* cls2 = (const float*)d_in[6];
    const float* bb2  = (const float*)d_in[7];
    const float* obj2 = (const float*)d_in[8];
    float* out = (float*)d_out;

    char* ws = (char*)d_ws;
    float*    keptScore = (float*)(ws);                  //   256,000 B
    float4*   keptBox   = (float4*)(ws + 256000);        // 1,024,000 B
    uint32_t* imgCnt    = (uint32_t*)(ws + 1280000);     //        32 B

    hipMemsetAsync(imgCnt, 0, NB * sizeof(uint32_t), stream);
    yolox_all<<<NB * NCLS, TBS, 0, stream>>>(cls0, bb0, obj0, cls1, bb1, obj1,
                                             cls2, bb2, obj2,
                                             keptScore, keptBox, imgCnt, out);
}